// Round 7
// baseline (170.689 us; speedup 1.0000x reference)
//
#include <hip/hip_runtime.h>
#include <hip/hip_bf16.h>
#include <stdint.h>

#define B_    2
#define N_    65536
#define M_    16384
#define K_    32
#define KP_   15
#define DIN_  64
#define DOUT_ 128
#define TM    16
#define WPITCH 968   // wgt LDS row pitch in bf16 (960 + 8 pad)

typedef __bf16 bf16x8 __attribute__((ext_vector_type(8)));
typedef float  f32x4  __attribute__((ext_vector_type(4)));
typedef float  f32x2  __attribute__((ext_vector_type(2)));

__device__ inline unsigned short f2bf(float f) {
    union { float f; unsigned int i; } v; v.f = f;
    unsigned int x = v.i;
    return (unsigned short)((x + 0x7fffu + ((x >> 16) & 1u)) >> 16);  // RNE
}

// ---- K1: features (B, Din, N) f32 -> featT (B, N+1, Din) bf16, row N zeroed ----
__global__ __launch_bounds__(256) void transpose_feats(const float* __restrict__ feats,
                                                       unsigned short* __restrict__ featT) {
    const int b  = blockIdx.y;
    const int n0 = blockIdx.x * 64;
    const int t  = threadIdx.x;
    if (n0 >= N_) {
        if (t < 32)
            ((unsigned int*)(featT + ((size_t)b * (N_ + 1) + N_) * DIN_))[t] = 0u;
        return;
    }
    __shared__ float tile[64][65];
    const int nl = t & 63, dl = t >> 6;
    #pragma unroll
    for (int i = 0; i < 16; ++i) {
        int d = dl + 4 * i;
        tile[d][nl] = feats[((size_t)b * DIN_ + d) * N_ + n0 + nl];
    }
    __syncthreads();
    const int d2 = (t & 31) * 2;
    const int nr = t >> 5;
    #pragma unroll
    for (int i = 0; i < 8; ++i) {
        int n = nr + 8 * i;
        unsigned int u = ((unsigned int)f2bf(tile[d2 + 1][n]) << 16) | f2bf(tile[d2][n]);
        ((unsigned int*)(featT + ((size_t)b * (N_ + 1) + n0 + n) * DIN_))[t & 31] = u;
    }
}

// ---- K2: weights (960,128) f32 -> fragment-major W^T bf16 ----
// frag q = otile*30 + ks; element [q][lane] = 8 bf16: W[kb+j][o], kb = ks*32+(lane>>4)*8,
// o = otile*16 + (lane&15).  Stage-2 B-frag load is then one coalesced 16B/lane read.
__global__ __launch_bounds__(256) void build_wtfrag(const float* __restrict__ w,
                                                    unsigned short* __restrict__ wf) {
    int q = blockIdx.x * 256 + threadIdx.x;     // uint4 index, 8*30*64 = 15360 total
    if (q >= 15360) return;
    int otile = q / 1920, r = q % 1920;
    int ks = r >> 6, lane = r & 63;
    int o  = otile * 16 + (lane & 15);
    int kb = ks * 32 + (lane >> 4) * 8;
    unsigned int d[4];
    #pragma unroll
    for (int j = 0; j < 4; ++j) {
        unsigned short lo = f2bf(w[(size_t)(kb + 2 * j) * 128 + o]);
        unsigned short hi = f2bf(w[(size_t)(kb + 2 * j + 1) * 128 + o]);
        d[j] = ((unsigned int)hi << 16) | lo;
    }
    *(uint4*)(wf + (size_t)q * 8) = make_uint4(d[0], d[1], d[2], d[3]);
}

// ---- K3: fused gather + kernel-weights + stage-1 + stage-2 MFMA -> out ----
__global__ __launch_bounds__(512, 1) void kpconv_fused(
    const float* __restrict__ points_xyz,
    const float* __restrict__ center_xyz,
    const int*   __restrict__ nidx,
    const float* __restrict__ kpts,
    const unsigned short* __restrict__ featT,
    const unsigned short* __restrict__ wtFrag,
    float* __restrict__ out) {

    __shared__ __align__(16) unsigned int  fbuf[TM * 32 * 32];     // 64 KB [m*32+k][d2]
    __shared__ __align__(16) float         wlds[TM * KP_ * 32];    // 30 KB [m][p][k]
    __shared__ __align__(16) unsigned short wgt[TM * WPITCH];      // 30.25 KB [m][pd]

    const int t  = threadIdx.x;
    const int b  = blockIdx.y;
    const int m0 = blockIdx.x * TM;
    const size_t ibase = ((size_t)b * M_ + m0) * K_;

    // (1) issue all feature gathers into regs (latency hides under w-compute)
    uint4 v[8];
    const int part = t & 7, rbase = t >> 3;           // rbase 0..63
    #pragma unroll
    for (int i = 0; i < 8; ++i) {
        int r = i * 64 + rbase;                       // r = m*32 + k, 0..511
        int n = nidx[ibase + r];
        v[i] = *(const uint4*)(featT + ((size_t)b * (N_ + 1) + n) * DIN_ + part * 8);
    }

    // (2) kernel-correlation weights: thread = (m = t>>5, k = t&31), all 512 active
    {
        const int m = t >> 5, k = t & 31;
        int n = nidx[ibase + t];
        float px, py, pz;
        if (n < N_) {
            const float* p = points_xyz + ((size_t)b * N_ + n) * 3;
            px = p[0]; py = p[1]; pz = p[2];
        } else {
            px = py = pz = -1000.0f;
        }
        const float* c = center_xyz + ((size_t)b * M_ + m0 + m) * 3;
        float dx = px - c[0], dy = py - c[1], dz = pz - c[2];
        float md = __builtin_amdgcn_sqrtf(dx * dx + dy * dy + dz * dz);
        #pragma unroll
        for (int s = 16; s > 0; s >>= 1)
            md = fmaxf(md, __shfl_xor(md, s));
        float rsig = __builtin_amdgcn_rcpf(md * (1.0f / 2.1f) + 1e-5f);
        #pragma unroll
        for (int p = 0; p < KP_; ++p) {
            float ex = dx - kpts[p * 3 + 0] * md;
            float ey = dy - kpts[p * 3 + 1] * md;
            float ez = dz - kpts[p * 3 + 2] * md;
            float wv = 1.0f - __builtin_amdgcn_sqrtf(ex * ex + ey * ey + ez * ez) * rsig;
            wlds[(m * KP_ + p) * 32 + k] = wv > 0.0f ? wv : 0.0f;  // k-indexed: conflict-free
        }
    }

    // (3) land gathers in LDS (vmcnt waits here, after w-compute)
    #pragma unroll
    for (int i = 0; i < 8; ++i)
        ((uint4*)fbuf)[(i * 64 + rbase) * 8 + part] = v[i];
    __syncthreads();

    // (4) stage-1: wgt[m][p*64+d] = sum_k w[m][p][k] * f[m][k][d]; packed-f32 FMA
    {
        const int m = t >> 5, d2 = t & 31;
        f32x2 acc[KP_];
        #pragma unroll
        for (int p = 0; p < KP_; ++p) acc[p] = (f32x2){0.f, 0.f};

        const unsigned int* fcol = &fbuf[(m * 32) * 32 + d2];
        const float* wbase = &wlds[m * KP_ * 32];

        #pragma unroll
        for (int k4 = 0; k4 < 8; ++k4) {
            f32x2 fv[4];
            #pragma unroll
            for (int j = 0; j < 4; ++j) {
                unsigned int u = fcol[(k4 * 4 + j) * 32];
                union { unsigned int i; float f; } lo, hi;
                lo.i = u << 16; hi.i = u & 0xffff0000u;
                fv[j] = (f32x2){lo.f, hi.f};
            }
            #pragma unroll
            for (int p = 0; p < KP_; ++p) {
                float4 w4 = *(const float4*)(wbase + p * 32 + k4 * 4);  // broadcast
                acc[p] += fv[0] * w4.x;
                acc[p] += fv[1] * w4.y;
                acc[p] += fv[2] * w4.z;
                acc[p] += fv[3] * w4.w;
            }
        }

        unsigned int* wrow = (unsigned int*)wgt;      // u32 pitch = WPITCH/2 = 484
        #pragma unroll
        for (int p = 0; p < KP_; ++p) {
            unsigned int u = ((unsigned int)f2bf(acc[p][1]) << 16) | f2bf(acc[p][0]);
            wrow[m * (WPITCH / 2) + p * 32 + d2] = u;
        }
    }
    __syncthreads();

    // (5) stage-2: out[16][128] = wgt[16][960] x W[960][128], MFMA, wave w = o-tile
    {
        const int w = t >> 6, lane = t & 63;
        const char* aBase = (const char*)wgt + (lane & 15) * (WPITCH * 2) + (lane >> 4) * 16;
        const unsigned short* bPtr = wtFrag + ((size_t)(w * 30) * 64 + lane) * 8;

        f32x4 dacc = {0.f, 0.f, 0.f, 0.f};
        // 5-deep B-frag register pipeline (named regs, compile-time indexed)
        bf16x8 b0 = *(const bf16x8*)(bPtr);
        bf16x8 b1 = *(const bf16x8*)(bPtr + 512);
        bf16x8 b2 = *(const bf16x8*)(bPtr + 1024);
        bf16x8 b3 = *(const bf16x8*)(bPtr + 1536);
        bf16x8 b4 = *(const bf16x8*)(bPtr + 2048);

        #define S2_STEP(BX, KS, LD)                                           \
            {                                                                 \
                bf16x8 a = *(const bf16x8*)(aBase + (KS) * 64);               \
                dacc = __builtin_amdgcn_mfma_f32_16x16x32_bf16(a, BX, dacc,   \
                                                               0, 0, 0);      \
                if ((LD) < 30) BX = *(const bf16x8*)(bPtr + (size_t)(LD) * 512); \
            }

        for (int mi = 0; mi < 6; ++mi) {
            int ks = mi * 5;
            S2_STEP(b0, ks + 0, ks + 5);
            S2_STEP(b1, ks + 1, ks + 6);
            S2_STEP(b2, ks + 2, ks + 7);
            S2_STEP(b3, ks + 3, ks + 8);
            S2_STEP(b4, ks + 4, ks + 9);
        }
        #undef S2_STEP

        // D: col = lane&15 = o-in-tile, rows = (lane>>4)*4 + j = m -> f32x4 store
        const int o = w * 16 + (lane & 15);
        float* dst = out + ((size_t)b * DOUT_ + o) * M_ + m0 + (lane >> 4) * 4;
        *(f32x4*)dst = dacc;
    }
}

extern "C" void kernel_launch(void* const* d_in, const int* in_sizes, int n_in,
                              void* d_out, int out_size, void* d_ws, size_t ws_size,
                              hipStream_t stream) {
    const float* points_xyz = (const float*)d_in[0];
    const float* features   = (const float*)d_in[1];
    const float* center_xyz = (const float*)d_in[2];
    const int*   nidx       = (const int*)d_in[3];
    const float* kpts       = (const float*)d_in[4];
    const float* weights    = (const float*)d_in[5];
    float* out = (float*)d_out;

    unsigned short* featT  = (unsigned short*)d_ws;                       // 16,777,472 B
    unsigned short* wtFrag = (unsigned short*)((char*)d_ws + 16777472);   //    245,760 B

    transpose_feats<<<dim3((N_ + 64) / 64, B_), 256, 0, stream>>>(features, featT);
    build_wtfrag<<<60, 256, 0, stream>>>(weights, wtFrag);
    kpconv_fused<<<dim3(M_ / TM, B_), 512, 0, stream>>>(points_xyz, center_xyz, nidx,
                                                        kpts, featT, wtFrag, out);
}